// Round 2
// baseline (469.045 us; speedup 1.0000x reference)
//
#include <hip/hip_runtime.h>

#define Dm 512
#define Fm 2048
#define Mm 8192    // B*S tokens
#define KTOT 18432 // 9*Fm

typedef __attribute__((ext_vector_type(8))) short short8;
typedef __attribute__((ext_vector_type(4))) float f32x4;

// ---------- helpers ----------

__device__ __forceinline__ unsigned short f2bf(float f) {
  unsigned u = __builtin_bit_cast(unsigned, f);
  u = (u + 0x7FFFu + ((u >> 16) & 1u)) >> 16;
  return (unsigned short)u;
}

__device__ __forceinline__ float fast_exp2(float x) {
  float r; asm("v_exp_f32 %0, %1" : "=v"(r) : "v"(x)); return r;
}
__device__ __forceinline__ float fast_rcp(float x) {
  float r; asm("v_rcp_f32 %0, %1" : "=v"(r) : "v"(x)); return r;
}

__device__ __forceinline__ void gload_lds16(const void* g, void* lp) {
  __builtin_amdgcn_global_load_lds(
      (const __attribute__((address_space(1))) void*)(unsigned long long)(g),
      (__attribute__((address_space(3))) void*)(unsigned)(unsigned long long)(lp),
      16, 0, 0);
}

__device__ __forceinline__ f32x4 mfma16(short8 a, short8 b, f32x4 c) {
  asm("v_mfma_f32_16x16x32_bf16 %0, %1, %2, %0" : "+v"(c) : "v"(a), "v"(b));
  return c;
}

// Fused wait+barrier as ONE memory-clobber asm: a full compiler memory fence.
// Prevents IR-level hoisting of LDS reads above the barrier (the vmcnt only
// covers THIS wave's global_load_lds; the barrier covers the other waves').
#define WAIT_BARRIER(n) asm volatile("s_waitcnt vmcnt(" #n ")\n\ts_barrier" ::: "memory")

// ---------- prep kernels ----------

__global__ void cvtx_k(const float* __restrict__ src, unsigned short* __restrict__ dst, int n) {
  int i = (blockIdx.x * 256 + threadIdx.x) * 4;
  if (i >= n) return;
  const float4 v = *(const float4*)(src + i);
  unsigned a = (unsigned)f2bf(v.x) | ((unsigned)f2bf(v.y) << 16);
  unsigned b = (unsigned)f2bf(v.z) | ((unsigned)f2bf(v.w) << 16);
  uint2 o; o.x = a; o.y = b;
  *(uint2*)(dst + i) = o;
}

__global__ void wts_k(const float* __restrict__ gp, const float* __restrict__ sg,
                      float* __restrict__ wts) {
  int t = blockIdx.x * 256 + threadIdx.x;
  if (t >= Mm) return;
  float s = sg[t];
  float om = 1.0f - s;
#pragma unroll
  for (int e = 0; e < 8; ++e) wts[t * 9 + e] = om * gp[t * 8 + e];
  wts[t * 9 + 8] = s;
}

// Merged weight transposes:
//  bid < 9216 : W1 [D][F] f32 -> W1T [e][F][D] bf16
//  bid >= 9216: W2 [F][D] f32 -> W2T [D][9F]   bf16 (expert e at col base e*F)
__global__ void wt_k(const float* __restrict__ W1, const float* __restrict__ Ws1,
                     const float* __restrict__ W2, const float* __restrict__ Ws2,
                     unsigned short* __restrict__ W1T, unsigned short* __restrict__ W2T) {
  __shared__ float tile[32][33];
  const int tx = threadIdx.x, ty = threadIdx.y;
  int bid = blockIdx.x;
  if (bid < 9216) {
    const int e = bid >> 10;
    const int rem = bid & 1023;
    const float* src = (e < 8) ? (W1 + (size_t)e * Dm * Fm) : Ws1;
    const int c0 = (rem & 63) << 5;    // F
    const int r0 = (rem >> 6) << 5;    // D
#pragma unroll
    for (int j = ty; j < 32; j += 8) tile[j][tx] = src[(size_t)(r0 + j) * Fm + c0 + tx];
    __syncthreads();
    unsigned short* de = W1T + (size_t)e * Fm * Dm;
#pragma unroll
    for (int j = ty; j < 32; j += 8) de[(size_t)(c0 + j) * Dm + r0 + tx] = f2bf(tile[tx][j]);
  } else {
    bid -= 9216;
    const int e = bid >> 10;
    const int rem = bid & 1023;
    const float* src = (e < 8) ? (W2 + (size_t)e * Fm * Dm) : Ws2;
    const int c0 = (rem & 15) << 5;    // D
    const int r0 = (rem >> 4) << 5;    // F
#pragma unroll
    for (int j = ty; j < 32; j += 8) tile[j][tx] = src[(size_t)(r0 + j) * Dm + c0 + tx];
    __syncthreads();
#pragma unroll
    for (int j = ty; j < 32; j += 8)
      W2T[(size_t)(c0 + j) * KTOT + (size_t)e * Fm + r0 + tx] = f2bf(tile[tx][j]);
  }
}

// ---------- GEMM1: Hs[m, el*F+f] = wts[m,eg] * gelu(X @ W1_eg + b1_eg) ----------
// gemm2's proven structure: 128(M) x 64(N) tile, BK=64, 4 waves (64x32/wave),
// 3-stage LDS pipeline with counted vmcnt(6): loads stay in flight across the
// single fused wait+barrier per K-step. NT = Dm/64 = 8 (unroll 1 to keep the
// rotation in a loop, matching gemm2 codegen). LDS 72 KiB -> 2 blocks/CU.
// L2-grouped swizzle: per expert, groups of (8 m-tiles x all 32 n-tiles).

__global__ __launch_bounds__(256)
void gemm1_k(const unsigned short* __restrict__ Xb,
             const unsigned short* __restrict__ W1T,
             const float* __restrict__ b1, const float* __restrict__ bs1,
             const float* __restrict__ wts,
             unsigned short* __restrict__ Hs,
             int gbase, int Gg, int ldH) {
  __shared__ __attribute__((aligned(16))) unsigned short As[3][128 * 64];
  __shared__ __attribute__((aligned(16))) unsigned short Bs[3][64 * 64];

  const int tid = threadIdx.x, l = tid & 63, w = tid >> 6;
  const int wr = w >> 1, wc = w & 1;            // wave tile 64(M) x 32(N)
  const int nwg = Gg << 11;                     // Gg * 2048 blocks
  const int wg = (blockIdx.x & 7) * (nwg >> 3) + (blockIdx.x >> 3);  // bijective (nwg%8==0)
  const int el = wg >> 11;
  const int rem = wg & 2047;
  const int grp = rem >> 8;          // 8 m-groups of 8 m-tiles per expert
  const int sub = rem & 255;         // 8 m x 32 n, n fastest
  const int tn = (sub & 31) << 6;
  const int tm = ((grp << 3) + (sub >> 5)) << 7;
  const int eg = gbase + el;
  const unsigned short* BT = W1T + (size_t)eg * Fm * Dm;
  const float* bias = (eg < 8) ? (b1 + (size_t)eg * Fm) : bs1;

  f32x4 acc[4][2];
  const f32x4 zz = {0.f, 0.f, 0.f, 0.f};
#pragma unroll
  for (int mi = 0; mi < 4; ++mi)
#pragma unroll
    for (int ni = 0; ni < 2; ++ni) acc[mi][ni] = zz;

  const int srow = tid >> 3;                    // 0..31
  const int sc = ((tid & 7) ^ (srow & 7)) << 3; // inverse-swizzled source col

  // 6 gload_lds per STAGE (4 A + 2 B)
#define STAGE1(buf, ks)                                                          \
  {                                                                              \
    _Pragma("unroll")                                                            \
    for (int i = 0; i < 4; ++i) {                                                \
      const int row = i * 32 + srow;                                             \
      gload_lds16(Xb + (size_t)(tm + row) * Dm + (ks) + sc,                      \
                  (char*)As[buf] + i * 4096 + tid * 16);                         \
    }                                                                            \
    _Pragma("unroll")                                                            \
    for (int i = 0; i < 2; ++i) {                                                \
      const int row = i * 32 + srow;                                             \
      gload_lds16(BT + (size_t)(tn + row) * Dm + (ks) + sc,                      \
                  (char*)Bs[buf] + i * 4096 + tid * 16);                         \
    }                                                                            \
  }

  STAGE1(0, 0);
  STAGE1(1, 64);

#pragma unroll 1
  for (int t = 0; t < 8; ++t) {       // Dm/64 = 8 K-steps
    const int cur = t % 3;
    // stage t complete; stage t+1's 6 loads may remain in flight
    if (t + 1 < 8) { WAIT_BARRIER(6); }
    else           { WAIT_BARRIER(0); }
    __builtin_amdgcn_sched_barrier(0);
    if (t + 2 < 8) {
      const int nb = (t + 2) % 3;
      STAGE1(nb, (t + 2) << 6);
    }
#pragma unroll
    for (int kk = 0; kk < 2; ++kk) {
      const int kbx = (kk * 64 + ((l >> 4) << 4)) ^ ((l & 7) << 4);  // swizzled read col
      short8 af[4], bfr[2];
#pragma unroll
      for (int mi = 0; mi < 4; ++mi)
        af[mi] = *(const short8*)((const char*)As[cur] + ((wr * 64 + mi * 16 + (l & 15)) << 7) + kbx);
#pragma unroll
      for (int ni = 0; ni < 2; ++ni)
        bfr[ni] = *(const short8*)((const char*)Bs[cur] + ((wc * 32 + ni * 16 + (l & 15)) << 7) + kbx);
#pragma unroll
      for (int mi = 0; mi < 4; ++mi)
#pragma unroll
        for (int ni = 0; ni < 2; ++ni)
          acc[mi][ni] = mfma16(af[mi], bfr[ni], acc[mi][ni]);
    }
  }
#undef STAGE1

  const int row0 = tm + wr * 64 + ((l >> 4) << 2);
  const int col0 = tn + wc * 32 + (l & 15);
  const size_t hb = (size_t)el * Fm;
  float bv[2];
#pragma unroll
  for (int ni = 0; ni < 2; ++ni) bv[ni] = bias[col0 + ni * 16];

  // gelu(v)*wt with folded constants: g = v*rcp(1+exp2(v*(A + B*v^2)))
  const float Ac = -2.3022120f;    // -2*0.7978845608*log2(e)
  const float Bc = -0.10294341f;   // Ac*0.044715

#pragma unroll
  for (int mi = 0; mi < 4; ++mi) {
#pragma unroll
    for (int r = 0; r < 4; ++r) {
      const int rr = row0 + mi * 16 + r;
      const float wt = wts[(size_t)rr * 9 + eg];
      float g[2];
#pragma unroll
      for (int ni = 0; ni < 2; ++ni) {
        const float v = acc[mi][ni][r] + bv[ni];
        const float t2 = v * fmaf(Bc, v * v, Ac);
        g[ni] = wt * v * fast_rcp(1.0f + fast_exp2(t2));
      }
      unsigned pk0;
      asm("v_cvt_pk_bf16_f32 %0, %1, %2" : "=v"(pk0) : "v"(g[0]), "v"(g[1]));
      unsigned short* hp = Hs + (size_t)rr * ldH + hb + col0;
      hp[0]  = (unsigned short)pk0;
      hp[16] = (unsigned short)(pk0 >> 16);
    }
  }
}

// ---------- GEMM2: out[m,d] (+)= Hs[m,0:Kt] @ W2Tg[d,0:Kt]^T  (+ gated bias on g0)
// 128(M) x 64(N) tile, BK=64, 4 waves (64x32/wave), register acc over concat-K.
// 3-stage LDS pipeline with counted vmcnt (T4): 12 loads in flight, fused
// wait+barrier (no vmcnt(0) drain mid-loop). Grid 512 = 2 blocks/CU.

__global__ __launch_bounds__(256)
void gemm2_k(const unsigned short* __restrict__ A, int lda,
             const unsigned short* __restrict__ BT, int ldb,
             float* __restrict__ out,
             const float* __restrict__ wts,
             const float* __restrict__ b2, const float* __restrict__ bs2,
             int Kt, int g0) {
  __shared__ __attribute__((aligned(16))) unsigned short As[3][128 * 64];
  __shared__ __attribute__((aligned(16))) unsigned short Bs[3][64 * 64];

  const int tid = threadIdx.x, l = tid & 63, w = tid >> 6;
  const int wr = w >> 1, wc = w & 1;            // wave tile 64(M) x 32(N)
  const int wg = (blockIdx.x & 7) * 64 + (blockIdx.x >> 3);
  const int gm = wg >> 6;                       // m-group
  const int sub = wg & 63;                      // 8m x 8n, n fastest
  const int tn = (sub & 7) << 6;
  const int tm = ((gm << 3) + (sub >> 3)) << 7;

  f32x4 acc[4][2];
  const f32x4 zz = {0.f, 0.f, 0.f, 0.f};
#pragma unroll
  for (int mi = 0; mi < 4; ++mi)
#pragma unroll
    for (int ni = 0; ni < 2; ++ni) acc[mi][ni] = zz;

  const int srow = tid >> 3;                    // 0..31
  const int sc = ((tid & 7) ^ (srow & 7)) << 3;

  // 6 gload_lds per STAGE (4 A + 2 B)
#define STAGE2(buf, ks)                                                          \
  {                                                                              \
    _Pragma("unroll")                                                            \
    for (int i = 0; i < 4; ++i) {                                                \
      const int row = i * 32 + srow;                                             \
      gload_lds16(A + (size_t)(tm + row) * lda + (ks) + sc,                      \
                  (char*)As[buf] + i * 4096 + tid * 16);                         \
    }                                                                            \
    _Pragma("unroll")                                                            \
    for (int i = 0; i < 2; ++i) {                                                \
      const int row = i * 32 + srow;                                             \
      gload_lds16(BT + (size_t)(tn + row) * ldb + (ks) + sc,                     \
                  (char*)Bs[buf] + i * 4096 + tid * 16);                         \
    }                                                                            \
  }

  const int NT = Kt >> 6;
  STAGE2(0, 0);
  STAGE2(1, 64);

#pragma unroll 1
  for (int t = 0; t < NT; ++t) {
    const int cur = t % 3;
    // stage t complete; stage t+1's 6 loads may remain in flight
    if (t + 1 < NT) { WAIT_BARRIER(6); }
    else            { WAIT_BARRIER(0); }
    __builtin_amdgcn_sched_barrier(0);
    if (t + 2 < NT) {
      const int nb = (t + 2) % 3;
      STAGE2(nb, (t + 2) << 6);
    }
#pragma unroll
    for (int kk = 0; kk < 2; ++kk) {
      const int kbx = (kk * 64 + ((l >> 4) << 4)) ^ ((l & 7) << 4);
      short8 af[4], bfr[2];
#pragma unroll
      for (int mi = 0; mi < 4; ++mi)
        af[mi] = *(const short8*)((const char*)As[cur] + ((wr * 64 + mi * 16 + (l & 15)) << 7) + kbx);
#pragma unroll
      for (int ni = 0; ni < 2; ++ni)
        bfr[ni] = *(const short8*)((const char*)Bs[cur] + ((wc * 32 + ni * 16 + (l & 15)) << 7) + kbx);
#pragma unroll
      for (int mi = 0; mi < 4; ++mi)
#pragma unroll
        for (int ni = 0; ni < 2; ++ni)
          acc[mi][ni] = mfma16(af[mi], bfr[ni], acc[mi][ni]);
    }
  }
#undef STAGE2

  const int row0 = tm + wr * 64 + ((l >> 4) << 2);
  const int col0 = tn + wc * 32 + (l & 15);

  if (g0) {
    float bcol[2][9];
#pragma unroll
    for (int ni = 0; ni < 2; ++ni) {
      const int c = col0 + ni * 16;
#pragma unroll
      for (int e = 0; e < 8; ++e) bcol[ni][e] = b2[(e << 9) + c];
      bcol[ni][8] = bs2[c];
    }
#pragma unroll
    for (int mi = 0; mi < 4; ++mi)
#pragma unroll
      for (int r = 0; r < 4; ++r) {
        const int rr = row0 + mi * 16 + r;
        const float* wrow = wts + (size_t)rr * 9;
#pragma unroll
        for (int ni = 0; ni < 2; ++ni) {
          float b = 0.f;
#pragma unroll
          for (int e = 0; e < 9; ++e) b += wrow[e] * bcol[ni][e];
          out[(size_t)rr * Dm + col0 + ni * 16] = acc[mi][ni][r] + b;
        }
      }
  } else {
#pragma unroll
    for (int mi = 0; mi < 4; ++mi)
#pragma unroll
      for (int r = 0; r < 4; ++r) {
        const size_t rb = (size_t)(row0 + mi * 16 + r) * Dm;
#pragma unroll
        for (int ni = 0; ni < 2; ++ni)
          out[rb + col0 + ni * 16] += acc[mi][ni][r];
      }
  }
}

// ---------- launch ----------

extern "C" void kernel_launch(void* const* d_in, const int* in_sizes, int n_in,
                              void* d_out, int out_size, void* d_ws, size_t ws_size,
                              hipStream_t stream) {
  const float* x   = (const float*)d_in[0];
  const float* gp  = (const float*)d_in[1];
  const float* sg  = (const float*)d_in[2];
  const float* W1  = (const float*)d_in[3];
  const float* b1  = (const float*)d_in[4];
  const float* W2  = (const float*)d_in[5];
  const float* b2  = (const float*)d_in[6];
  const float* Ws1 = (const float*)d_in[7];
  const float* bs1 = (const float*)d_in[8];
  const float* Ws2 = (const float*)d_in[9];
  const float* bs2 = (const float*)d_in[10];
  float* out = (float*)d_out;

  const size_t szXb  = (size_t)Mm * Dm * 2;        //  8,388,608
  const size_t szWts = (size_t)Mm * 9 * 4;         //    294,912
  const size_t szW1T = (size_t)9 * Fm * Dm * 2;    // 18,874,368
  const size_t szW2T = (size_t)9 * Fm * Dm * 2;    // 18,874,368
  const size_t base  = szXb + szWts + szW1T + szW2T;

  int G;
  if      (ws_size >= base + (size_t)Mm * 9 * Fm * 2) G = 9; // 348.4 MB
  else if (ws_size >= base + (size_t)Mm * 3 * Fm * 2) G = 3; // 147.1 MB
  else if (ws_size >= base + (size_t)Mm * 2 * Fm * 2) G = 2; // 113.5 MB
  else if (ws_size >= base + (size_t)Mm * 1 * Fm * 2) G = 1; //  80.0 MB
  else return;

  char* ws = (char*)d_ws;
  unsigned short* Xb  = (unsigned short*)(ws);
  float*          wts = (float*)(ws + szXb);
  unsigned short* W1T = (unsigned short*)(ws + szXb + szWts);
  unsigned short* W2T = (unsigned short*)(ws + szXb + szWts + szW1T);
  unsigned short* Hs  = (unsigned short*)(ws + base);
  const int ldH = G * Fm;

  cvtx_k<<<dim3((Mm * Dm) / 1024), dim3(256), 0, stream>>>(x, Xb, Mm * Dm);
  wts_k<<<dim3(Mm / 256), dim3(256), 0, stream>>>(gp, sg, wts);
  wt_k<<<dim3(2 * 9 * 1024), dim3(32, 8), 0, stream>>>(W1, Ws1, W2, Ws2, W1T, W2T);

  for (int gb = 0; gb < 9; gb += G) {
    const int Gg = (9 - gb < G) ? (9 - gb) : G;
    gemm1_k<<<dim3(Gg * 2048), dim3(256), 0, stream>>>(
        Xb, W1T, b1, bs1, wts, Hs, gb, Gg, ldH);
    gemm2_k<<<dim3(512), dim3(256), 0, stream>>>(
        Hs, ldH, W2T + (size_t)gb * Fm, KTOT, out, wts, b2, bs2, Gg * Fm, gb == 0 ? 1 : 0);
  }
}

// Round 3
// 422.029 us; speedup vs baseline: 1.1114x; 1.1114x over previous
//
#include <hip/hip_runtime.h>

#define Dm 512
#define Fm 2048
#define Mm 8192    // B*S tokens
#define KTOT 18432 // 9*Fm

typedef __attribute__((ext_vector_type(8))) short short8;
typedef __attribute__((ext_vector_type(4))) float f32x4;

// ---------- helpers ----------

__device__ __forceinline__ unsigned short f2bf(float f) {
  unsigned u = __builtin_bit_cast(unsigned, f);
  u = (u + 0x7FFFu + ((u >> 16) & 1u)) >> 16;
  return (unsigned short)u;
}

__device__ __forceinline__ float fast_exp2(float x) {
  float r; asm("v_exp_f32 %0, %1" : "=v"(r) : "v"(x)); return r;
}
__device__ __forceinline__ float fast_rcp(float x) {
  float r; asm("v_rcp_f32 %0, %1" : "=v"(r) : "v"(x)); return r;
}

__device__ __forceinline__ void gload_lds16(const void* g, void* lp) {
  __builtin_amdgcn_global_load_lds(
      (const __attribute__((address_space(1))) void*)(unsigned long long)(g),
      (__attribute__((address_space(3))) void*)(unsigned)(unsigned long long)(lp),
      16, 0, 0);
}

__device__ __forceinline__ f32x4 mfma16(short8 a, short8 b, f32x4 c) {
  asm("v_mfma_f32_16x16x32_bf16 %0, %1, %2, %0" : "+v"(c) : "v"(a), "v"(b));
  return c;
}

// Fused wait+barrier as ONE memory-clobber asm: a full compiler memory fence.
// Prevents IR-level hoisting of LDS reads above the barrier (the vmcnt only
// covers THIS wave's global_load_lds; the barrier covers the other waves').
#define WAIT_BARRIER(n) asm volatile("s_waitcnt vmcnt(" #n ")\n\ts_barrier" ::: "memory")

// ---------- prep kernels ----------

__global__ void cvtx_k(const float* __restrict__ src, unsigned short* __restrict__ dst, int n) {
  int i = (blockIdx.x * 256 + threadIdx.x) * 4;
  if (i >= n) return;
  const float4 v = *(const float4*)(src + i);
  unsigned a = (unsigned)f2bf(v.x) | ((unsigned)f2bf(v.y) << 16);
  unsigned b = (unsigned)f2bf(v.z) | ((unsigned)f2bf(v.w) << 16);
  uint2 o; o.x = a; o.y = b;
  *(uint2*)(dst + i) = o;
}

__global__ void wts_k(const float* __restrict__ gp, const float* __restrict__ sg,
                      float* __restrict__ wts) {
  int t = blockIdx.x * 256 + threadIdx.x;
  if (t >= Mm) return;
  float s = sg[t];
  float om = 1.0f - s;
#pragma unroll
  for (int e = 0; e < 8; ++e) wts[t * 9 + e] = om * gp[t * 8 + e];
  wts[t * 9 + 8] = s;
}

// Merged weight transposes:
//  bid < 9216 : W1 [D][F] f32 -> W1T [e][F][D] bf16
//  bid >= 9216: W2 [F][D] f32 -> W2T [D][9F]   bf16 (expert e at col base e*F)
__global__ void wt_k(const float* __restrict__ W1, const float* __restrict__ Ws1,
                     const float* __restrict__ W2, const float* __restrict__ Ws2,
                     unsigned short* __restrict__ W1T, unsigned short* __restrict__ W2T) {
  __shared__ float tile[32][33];
  const int tx = threadIdx.x, ty = threadIdx.y;
  int bid = blockIdx.x;
  if (bid < 9216) {
    const int e = bid >> 10;
    const int rem = bid & 1023;
    const float* src = (e < 8) ? (W1 + (size_t)e * Dm * Fm) : Ws1;
    const int c0 = (rem & 63) << 5;    // F
    const int r0 = (rem >> 6) << 5;    // D
#pragma unroll
    for (int j = ty; j < 32; j += 8) tile[j][tx] = src[(size_t)(r0 + j) * Fm + c0 + tx];
    __syncthreads();
    unsigned short* de = W1T + (size_t)e * Fm * Dm;
#pragma unroll
    for (int j = ty; j < 32; j += 8) de[(size_t)(c0 + j) * Dm + r0 + tx] = f2bf(tile[tx][j]);
  } else {
    bid -= 9216;
    const int e = bid >> 10;
    const int rem = bid & 1023;
    const float* src = (e < 8) ? (W2 + (size_t)e * Fm * Dm) : Ws2;
    const int c0 = (rem & 15) << 5;    // D
    const int r0 = (rem >> 4) << 5;    // F
#pragma unroll
    for (int j = ty; j < 32; j += 8) tile[j][tx] = src[(size_t)(r0 + j) * Dm + c0 + tx];
    __syncthreads();
#pragma unroll
    for (int j = ty; j < 32; j += 8)
      W2T[(size_t)(c0 + j) * KTOT + (size_t)e * Fm + r0 + tx] = f2bf(tile[tx][j]);
  }
}

// ---------- GEMM1: Hs[m, el*F+f] = wts[m,eg] * gelu(X @ W1_eg + b1_eg) ----------
// 128x128 tile, BK=64, 4 waves, XOR-swizzled LDS, double-buffered staging
// (round-0 proven structure). B-columns permuted in LDS (r=16n+c -> 4c+n per
// 64-row block) so each thread's 4 output cols are CONTIGUOUS: epilogue is one
// uint2 (4 bf16) store per row instead of 4 scattered u16 stores; bias loads
// as float4. Memory image of Hs identical to the unpermuted version.

__global__ __launch_bounds__(256)
void gemm1_k(const unsigned short* __restrict__ Xb,
             const unsigned short* __restrict__ W1T,
             const float* __restrict__ b1, const float* __restrict__ bs1,
             const float* __restrict__ wts,
             unsigned short* __restrict__ Hs,
             int gbase, int Gg, int ldH) {
  __shared__ __attribute__((aligned(16))) unsigned short As[2][128 * 64];
  __shared__ __attribute__((aligned(16))) unsigned short Bs[2][128 * 64];

  const int tid = threadIdx.x, l = tid & 63, w = tid >> 6;
  const int wr = w >> 1, wc = w & 1;
  const int nwg = Gg << 10;
  const int wg = (blockIdx.x & 7) * (nwg >> 3) + (blockIdx.x >> 3);  // bijective (nwg%8==0)
  const int el = wg >> 10;
  const int rem = wg & 1023;
  const int grp = rem >> 7;          // 8 m-groups per expert
  const int sub = rem & 127;         // 8 m x 16 n, n fastest
  const int tn = (sub & 15) << 7;
  const int tm = ((grp << 3) + (sub >> 4)) << 7;
  const int eg = gbase + el;
  const unsigned short* BT = W1T + (size_t)eg * Fm * Dm;
  const float* bias = (eg < 8) ? (b1 + (size_t)eg * Fm) : bs1;

  f32x4 acc[4][4];
  const f32x4 zz = {0.f, 0.f, 0.f, 0.f};
#pragma unroll
  for (int mi = 0; mi < 4; ++mi)
#pragma unroll
    for (int ni = 0; ni < 4; ++ni) acc[mi][ni] = zz;

  const int srow = tid >> 3;
  const int sc = ((tid & 7) ^ (srow & 7)) << 3;   // inverse-swizzled source col

  // B row permutation within each 64-row block: LDS row (64a + 16n + c) holds
  // global col (64a + 4c + n)  => frag ni, lane c -> global col 4c + ni.
#define BPERM1(r) (((r) & 64) | (((r) & 15) << 2) | (((r) >> 4) & 3))

#define STAGE1(buf, ks)                                                          \
  {                                                                              \
    _Pragma("unroll")                                                            \
    for (int i = 0; i < 4; ++i) {                                                \
      const int row = i * 32 + srow;                                             \
      gload_lds16(Xb + (size_t)(tm + row) * Dm + (ks) + sc,                      \
                  (char*)As[buf] + i * 4096 + tid * 16);                         \
      gload_lds16(BT + (size_t)(tn + BPERM1(row)) * Dm + (ks) + sc,              \
                  (char*)Bs[buf] + i * 4096 + tid * 16);                         \
    }                                                                            \
  }

  STAGE1(0, 0);
  __syncthreads();

  for (int t = 0; t < 8; ++t) {       // Dm/64 = 8 K-steps
    const int cur = t & 1;
    if (t < 7) STAGE1(cur ^ 1, (t + 1) << 6);
#pragma unroll
    for (int kk = 0; kk < 2; ++kk) {
      const int kbx = (kk * 64 + ((l >> 4) << 4)) ^ ((l & 7) << 4);  // swizzled read col
      short8 af[4], bfr[4];
#pragma unroll
      for (int mi = 0; mi < 4; ++mi)
        af[mi] = *(const short8*)((const char*)As[cur] + ((wr * 64 + mi * 16 + (l & 15)) << 7) + kbx);
#pragma unroll
      for (int ni = 0; ni < 4; ++ni)
        bfr[ni] = *(const short8*)((const char*)Bs[cur] + ((wc * 64 + ni * 16 + (l & 15)) << 7) + kbx);
#pragma unroll
      for (int mi = 0; mi < 4; ++mi)
#pragma unroll
        for (int ni = 0; ni < 4; ++ni)
          acc[mi][ni] = mfma16(af[mi], bfr[ni], acc[mi][ni]);
    }
    if (t < 7) __syncthreads();
  }
#undef STAGE1
#undef BPERM1

  const int row0 = tm + wr * 64 + ((l >> 4) << 2);
  const int col0 = tn + wc * 64 + ((l & 15) << 2);   // 4 contiguous output cols
  const size_t hb = (size_t)el * Fm;
  const float4 bv = *(const float4*)(bias + col0);

  // gelu(v)*wt with folded constants: g = v*rcp(1+exp2(v*(A + B*v^2)))
  const float Ac = -2.3022120f;    // -2*0.7978845608*log2(e)
  const float Bc = -0.10294341f;   // Ac*0.044715

#pragma unroll
  for (int mi = 0; mi < 4; ++mi) {
#pragma unroll
    for (int r = 0; r < 4; ++r) {
      const int rr = row0 + mi * 16 + r;
      const float wt = wts[(size_t)rr * 9 + eg];
      float g[4];
      const float bvv[4] = {bv.x, bv.y, bv.z, bv.w};
#pragma unroll
      for (int ni = 0; ni < 4; ++ni) {
        const float v = acc[mi][ni][r] + bvv[ni];
        const float t2 = v * fmaf(Bc, v * v, Ac);
        g[ni] = wt * v * fast_rcp(1.0f + fast_exp2(t2));
      }
      uint2 pk;
      asm("v_cvt_pk_bf16_f32 %0, %1, %2" : "=v"(pk.x) : "v"(g[0]), "v"(g[1]));
      asm("v_cvt_pk_bf16_f32 %0, %1, %2" : "=v"(pk.y) : "v"(g[2]), "v"(g[3]));
      *(uint2*)(Hs + (size_t)rr * ldH + hb + col0) = pk;   // 4 bf16, 8B coalesced
    }
  }
}

// ---------- GEMM2: out[m,d] (+)= Hs[m,0:Kt] @ W2Tg[d,0:Kt]^T  (+ gated bias on g0)
// 128(M) x 64(N) tile, BK=64, 4 waves (64x32/wave), register acc over concat-K.
// 3-stage LDS pipeline with counted vmcnt (T4): 12 loads in flight, fused
// wait+barrier (no vmcnt(0) drain mid-loop). Grid 512 = 2 blocks/CU.
// B-columns permuted (r=16n+c -> 2c+n per 32-row block) so each thread's 2
// output cols are contiguous: float2 stores / loads in the epilogue.

__global__ __launch_bounds__(256)
void gemm2_k(const unsigned short* __restrict__ A, int lda,
             const unsigned short* __restrict__ BT, int ldb,
             float* __restrict__ out,
             const float* __restrict__ wts,
             const float* __restrict__ b2, const float* __restrict__ bs2,
             int Kt, int g0) {
  __shared__ __attribute__((aligned(16))) unsigned short As[3][128 * 64];
  __shared__ __attribute__((aligned(16))) unsigned short Bs[3][64 * 64];

  const int tid = threadIdx.x, l = tid & 63, w = tid >> 6;
  const int wr = w >> 1, wc = w & 1;            // wave tile 64(M) x 32(N)
  const int wg = (blockIdx.x & 7) * 64 + (blockIdx.x >> 3);
  const int gm = wg >> 6;                       // m-group
  const int sub = wg & 63;                      // 8m x 8n, n fastest
  const int tn = (sub & 7) << 6;
  const int tm = ((gm << 3) + (sub >> 3)) << 7;

  f32x4 acc[4][2];
  const f32x4 zz = {0.f, 0.f, 0.f, 0.f};
#pragma unroll
  for (int mi = 0; mi < 4; ++mi)
#pragma unroll
    for (int ni = 0; ni < 2; ++ni) acc[mi][ni] = zz;

  const int srow = tid >> 3;                    // 0..31
  const int sc = ((tid & 7) ^ (srow & 7)) << 3;

  // B row permutation within each 32-row block: LDS row (32a + 16n + c) holds
  // global col (32a + 2c + n)  => frag ni, lane c -> global col 2c + ni.
#define BPERM2(r) (((r) & 32) | (((r) & 15) << 1) | (((r) >> 4) & 1))

  // 6 gload_lds per STAGE (4 A + 2 B)
#define STAGE2(buf, ks)                                                          \
  {                                                                              \
    _Pragma("unroll")                                                            \
    for (int i = 0; i < 4; ++i) {                                                \
      const int row = i * 32 + srow;                                             \
      gload_lds16(A + (size_t)(tm + row) * lda + (ks) + sc,                      \
                  (char*)As[buf] + i * 4096 + tid * 16);                         \
    }                                                                            \
    _Pragma("unroll")                                                            \
    for (int i = 0; i < 2; ++i) {                                                \
      const int row = i * 32 + srow;                                             \
      gload_lds16(BT + (size_t)(tn + BPERM2(row)) * ldb + (ks) + sc,             \
                  (char*)Bs[buf] + i * 4096 + tid * 16);                         \
    }                                                                            \
  }

  const int NT = Kt >> 6;
  STAGE2(0, 0);
  STAGE2(1, 64);

#pragma unroll 1
  for (int t = 0; t < NT; ++t) {
    const int cur = t % 3;
    // stage t complete; stage t+1's 6 loads may remain in flight
    if (t + 1 < NT) { WAIT_BARRIER(6); }
    else            { WAIT_BARRIER(0); }
    __builtin_amdgcn_sched_barrier(0);
    if (t + 2 < NT) {
      const int nb = (t + 2) % 3;
      STAGE2(nb, (t + 2) << 6);
    }
#pragma unroll
    for (int kk = 0; kk < 2; ++kk) {
      const int kbx = (kk * 64 + ((l >> 4) << 4)) ^ ((l & 7) << 4);
      short8 af[4], bfr[2];
#pragma unroll
      for (int mi = 0; mi < 4; ++mi)
        af[mi] = *(const short8*)((const char*)As[cur] + ((wr * 64 + mi * 16 + (l & 15)) << 7) + kbx);
#pragma unroll
      for (int ni = 0; ni < 2; ++ni)
        bfr[ni] = *(const short8*)((const char*)Bs[cur] + ((wc * 32 + ni * 16 + (l & 15)) << 7) + kbx);
#pragma unroll
      for (int mi = 0; mi < 4; ++mi)
#pragma unroll
        for (int ni = 0; ni < 2; ++ni)
          acc[mi][ni] = mfma16(af[mi], bfr[ni], acc[mi][ni]);
    }
  }
#undef STAGE2
#undef BPERM2

  const int row0 = tm + wr * 64 + ((l >> 4) << 2);
  const int col0 = tn + wc * 32 + ((l & 15) << 1);   // 2 contiguous output cols

  if (g0) {
    float bcol[2][9];
#pragma unroll
    for (int ni = 0; ni < 2; ++ni) {
      const int c = col0 + ni;
#pragma unroll
      for (int e = 0; e < 8; ++e) bcol[ni][e] = b2[(e << 9) + c];
      bcol[ni][8] = bs2[c];
    }
#pragma unroll
    for (int mi = 0; mi < 4; ++mi)
#pragma unroll
      for (int r = 0; r < 4; ++r) {
        const int rr = row0 + mi * 16 + r;
        const float* wrow = wts + (size_t)rr * 9;
        float b0 = 0.f, b1v = 0.f;
#pragma unroll
        for (int e = 0; e < 9; ++e) { b0 += wrow[e] * bcol[0][e]; b1v += wrow[e] * bcol[1][e]; }
        float2 o;
        o.x = acc[mi][0][r] + b0;
        o.y = acc[mi][1][r] + b1v;
        *(float2*)(out + (size_t)rr * Dm + col0) = o;
      }
  } else {
#pragma unroll
    for (int mi = 0; mi < 4; ++mi)
#pragma unroll
      for (int r = 0; r < 4; ++r) {
        float* p = out + (size_t)(row0 + mi * 16 + r) * Dm + col0;
        float2 o = *(float2*)p;
        o.x += acc[mi][0][r];
        o.y += acc[mi][1][r];
        *(float2*)p = o;
      }
  }
}

// ---------- launch ----------

extern "C" void kernel_launch(void* const* d_in, const int* in_sizes, int n_in,
                              void* d_out, int out_size, void* d_ws, size_t ws_size,
                              hipStream_t stream) {
  const float* x   = (const float*)d_in[0];
  const float* gp  = (const float*)d_in[1];
  const float* sg  = (const float*)d_in[2];
  const float* W1  = (const float*)d_in[3];
  const float* b1  = (const float*)d_in[4];
  const float* W2  = (const float*)d_in[5];
  const float* b2  = (const float*)d_in[6];
  const float* Ws1 = (const float*)d_in[7];
  const float* bs1 = (const float*)d_in[8];
  const float* Ws2 = (const float*)d_in[9];
  const float* bs2 = (const float*)d_in[10];
  float* out = (float*)d_out;

  const size_t szXb  = (size_t)Mm * Dm * 2;        //  8,388,608
  const size_t szWts = (size_t)Mm * 9 * 4;         //    294,912
  const size_t szW1T = (size_t)9 * Fm * Dm * 2;    // 18,874,368
  const size_t szW2T = (size_t)9 * Fm * Dm * 2;    // 18,874,368
  const size_t base  = szXb + szWts + szW1T + szW2T;

  int G;
  if      (ws_size >= base + (size_t)Mm * 9 * Fm * 2) G = 9; // 348.4 MB
  else if (ws_size >= base + (size_t)Mm * 3 * Fm * 2) G = 3; // 147.1 MB
  else if (ws_size >= base + (size_t)Mm * 2 * Fm * 2) G = 2; // 113.5 MB
  else if (ws_size >= base + (size_t)Mm * 1 * Fm * 2) G = 1; //  80.0 MB
  else return;

  char* ws = (char*)d_ws;
  unsigned short* Xb  = (unsigned short*)(ws);
  float*          wts = (float*)(ws + szXb);
  unsigned short* W1T = (unsigned short*)(ws + szXb + szWts);
  unsigned short* W2T = (unsigned short*)(ws + szXb + szWts + szW1T);
  unsigned short* Hs  = (unsigned short*)(ws + base);
  const int ldH = G * Fm;

  cvtx_k<<<dim3((Mm * Dm) / 1024), dim3(256), 0, stream>>>(x, Xb, Mm * Dm);
  wts_k<<<dim3(Mm / 256), dim3(256), 0, stream>>>(gp, sg, wts);
  wt_k<<<dim3(2 * 9 * 1024), dim3(32, 8), 0, stream>>>(W1, Ws1, W2, Ws2, W1T, W2T);

  for (int gb = 0; gb < 9; gb += G) {
    const int Gg = (9 - gb < G) ? (9 - gb) : G;
    gemm1_k<<<dim3(Gg * 1024), dim3(256), 0, stream>>>(
        Xb, W1T, b1, bs1, wts, Hs, gb, Gg, ldH);
    gemm2_k<<<dim3(512), dim3(256), 0, stream>>>(
        Hs, ldH, W2T + (size_t)gb * Fm, KTOT, out, wts, b2, bs2, Gg * Fm, gb == 0 ? 1 : 0);
  }
}